// Round 1
// baseline (1336.757 us; speedup 1.0000x reference)
//
#include <hip/hip_runtime.h>
#include <math.h>

// MultiHeadAttention: B=2,S=2048,D=768,H=12,depth=64
// out = (softmax(mask(QK^T/8)) V) Wo^T + bo ; also returns attn itself.
// d_out = [out (B*S*D) | attn (B*H*S*S)] fp32.
constexpr int B_ = 2, S_ = 2048, D_ = 768, H_ = 12, DP_ = 64;
constexpr int M_ = B_ * S_;                         // 4096 rows
constexpr size_t HS_ELEMS = (size_t)B_ * H_ * S_ * DP_;  // head-split tensor elems
constexpr size_t OUT_ELEMS = (size_t)M_ * D_;

// ---------------------------------------------------------------------------
// GEMM  Y = X @ W^T + bias.   X:[M,768] row-major, W:[768,768] row-major
// (both contiguous in K). 64x64 tile, BK=16, 256 threads, 4x4 per thread.
// HEADSPLIT: write Y into [B,H,S,64]; else flat [M,768].
// Note: N-tile (64) == depth, so blockIdx.y == head index when headsplit.
// ---------------------------------------------------------------------------
template <bool HEADSPLIT>
__global__ __launch_bounds__(256) void gemm_xwt(const float* __restrict__ X,
                                                const float* __restrict__ W,
                                                const float* __restrict__ bias,
                                                float* __restrict__ Y) {
  __shared__ float As[16][65];  // [k][m], +1 pad
  __shared__ float Bs[16][65];  // [k][n]
  const int K = D_;
  const int bm = blockIdx.x, bn = blockIdx.y;
  const int tid = threadIdx.x;
  const int tx = tid & 15, ty = tid >> 4;
  const int lm = tid >> 2, lk = (tid & 3) << 2;
  const float* Xrow = X + (size_t)(bm * 64 + lm) * K;
  const float* Wrow = W + (size_t)(bn * 64 + lm) * K;
  float acc[4][4] = {};
  for (int k0 = 0; k0 < K; k0 += 16) {
    float4 av = *(const float4*)(Xrow + k0 + lk);
    float4 bv = *(const float4*)(Wrow + k0 + lk);
    __syncthreads();  // protect previous iteration's LDS reads
    As[lk + 0][lm] = av.x; As[lk + 1][lm] = av.y;
    As[lk + 2][lm] = av.z; As[lk + 3][lm] = av.w;
    Bs[lk + 0][lm] = bv.x; Bs[lk + 1][lm] = bv.y;
    Bs[lk + 2][lm] = bv.z; Bs[lk + 3][lm] = bv.w;
    __syncthreads();
#pragma unroll
    for (int kk = 0; kk < 16; ++kk) {
      float a[4], b[4];
#pragma unroll
      for (int i = 0; i < 4; ++i) a[i] = As[kk][ty * 4 + i];
#pragma unroll
      for (int j = 0; j < 4; ++j) b[j] = Bs[kk][tx * 4 + j];
#pragma unroll
      for (int i = 0; i < 4; ++i)
#pragma unroll
        for (int j = 0; j < 4; ++j) acc[i][j] += a[i] * b[j];
    }
  }
  const int n0 = bn * 64 + tx * 4;
  const float4 b4 = *(const float4*)(bias + n0);
#pragma unroll
  for (int i = 0; i < 4; ++i) {
    const int m = bm * 64 + ty * 4 + i;
    float4 o;
    o.x = acc[i][0] + b4.x; o.y = acc[i][1] + b4.y;
    o.z = acc[i][2] + b4.z; o.w = acc[i][3] + b4.w;
    if (HEADSPLIT) {
      const int b = m >> 11, s = m & (S_ - 1);
      // head == bn, d == tx*4
      *(float4*)(Y + (((size_t)b * H_ + bn) * S_ + s) * DP_ + tx * 4) = o;
    } else {
      *(float4*)(Y + (size_t)m * D_ + n0) = o;
    }
  }
}

// ---------------------------------------------------------------------------
// Scores: per (b,h)  P = (Q @ K^T) / 8.   Q,K: [S,64] head-split slices.
// Same X@W^T structure (both contiguous in K=64). Output [S,S] row-major.
// ---------------------------------------------------------------------------
__global__ __launch_bounds__(256) void gemm_scores(const float* __restrict__ Qh,
                                                   const float* __restrict__ Kh,
                                                   float* __restrict__ P) {
  __shared__ float As[16][65];
  __shared__ float Bs[16][65];
  const int bh = blockIdx.z;
  const float* Qb = Qh + (size_t)bh * S_ * DP_;
  const float* Kb = Kh + (size_t)bh * S_ * DP_;
  float* Pb = P + (size_t)bh * S_ * S_;
  const int bm = blockIdx.x, bn = blockIdx.y;
  const int tid = threadIdx.x;
  const int tx = tid & 15, ty = tid >> 4;
  const int lm = tid >> 2, lk = (tid & 3) << 2;
  float acc[4][4] = {};
  for (int k0 = 0; k0 < DP_; k0 += 16) {
    float4 av = *(const float4*)(Qb + (size_t)(bm * 64 + lm) * DP_ + k0 + lk);
    float4 bv = *(const float4*)(Kb + (size_t)(bn * 64 + lm) * DP_ + k0 + lk);
    __syncthreads();
    As[lk + 0][lm] = av.x; As[lk + 1][lm] = av.y;
    As[lk + 2][lm] = av.z; As[lk + 3][lm] = av.w;
    Bs[lk + 0][lm] = bv.x; Bs[lk + 1][lm] = bv.y;
    Bs[lk + 2][lm] = bv.z; Bs[lk + 3][lm] = bv.w;
    __syncthreads();
#pragma unroll
    for (int kk = 0; kk < 16; ++kk) {
      float a[4], b[4];
#pragma unroll
      for (int i = 0; i < 4; ++i) a[i] = As[kk][ty * 4 + i];
#pragma unroll
      for (int j = 0; j < 4; ++j) b[j] = Bs[kk][tx * 4 + j];
#pragma unroll
      for (int i = 0; i < 4; ++i)
#pragma unroll
        for (int j = 0; j < 4; ++j) acc[i][j] += a[i] * b[j];
    }
  }
  const float scale = 0.125f;  // 1/sqrt(64)
#pragma unroll
  for (int i = 0; i < 4; ++i) {
    const int q = bm * 64 + ty * 4 + i;
    float4 o;
    o.x = acc[i][0] * scale; o.y = acc[i][1] * scale;
    o.z = acc[i][2] * scale; o.w = acc[i][3] * scale;
    *(float4*)(Pb + (size_t)q * S_ + bn * 64 + tx * 4) = o;
  }
}

// ---------------------------------------------------------------------------
// Row softmax in place over attn rows (length S), with key mask [B,1,1,S].
// One 256-thread block per row; 8 elements (2 float4) per thread.
// ---------------------------------------------------------------------------
__global__ __launch_bounds__(256) void softmax_rows(float* __restrict__ P,
                                                    const int* __restrict__ mask) {
  const int row = blockIdx.x;       // bh*S + q
  const int bh = row >> 11;         // /S_
  const int b = bh / H_;
  float4* p4 = (float4*)(P + (size_t)row * S_);
  const int4* m4 = (const int4*)(mask + (size_t)b * S_);
  const int t = threadIdx.x;
  __shared__ float red[8];

  float4 v[2];
  float mx = -__builtin_inff();
#pragma unroll
  for (int r = 0; r < 2; ++r) {
    const int i4 = r * 256 + t;
    float4 val = p4[i4];
    const int4 mm = m4[i4];
    if (mm.x == 0) val.x = -__builtin_inff();
    if (mm.y == 0) val.y = -__builtin_inff();
    if (mm.z == 0) val.z = -__builtin_inff();
    if (mm.w == 0) val.w = -__builtin_inff();
    v[r] = val;
    mx = fmaxf(mx, fmaxf(fmaxf(val.x, val.y), fmaxf(val.z, val.w)));
  }
#pragma unroll
  for (int o = 32; o > 0; o >>= 1) mx = fmaxf(mx, __shfl_down(mx, o));
  const int wv = t >> 6, ln = t & 63;
  if (ln == 0) red[wv] = mx;
  __syncthreads();
  mx = fmaxf(fmaxf(red[0], red[1]), fmaxf(red[2], red[3]));

  float sum = 0.f;
#pragma unroll
  for (int r = 0; r < 2; ++r) {
    float4 val = v[r];
    val.x = (val.x == -__builtin_inff()) ? 0.f : __expf(val.x - mx);
    val.y = (val.y == -__builtin_inff()) ? 0.f : __expf(val.y - mx);
    val.z = (val.z == -__builtin_inff()) ? 0.f : __expf(val.z - mx);
    val.w = (val.w == -__builtin_inff()) ? 0.f : __expf(val.w - mx);
    v[r] = val;
    sum += val.x + val.y + val.z + val.w;
  }
#pragma unroll
  for (int o = 32; o > 0; o >>= 1) sum += __shfl_down(sum, o);
  if (ln == 0) red[4 + wv] = sum;
  __syncthreads();
  sum = red[4] + red[5] + red[6] + red[7];
  const float inv = 1.0f / sum;
#pragma unroll
  for (int r = 0; r < 2; ++r) {
    float4 val = v[r];
    val.x *= inv; val.y *= inv; val.z *= inv; val.w *= inv;
    p4[r * 256 + t] = val;
  }
}

// ---------------------------------------------------------------------------
// ctx = P @ V per (b,h).  P:[S,S] (contig in k), V:[S,64] (contig in n).
// Writes ctx directly in concat layout [B,S,H*64] so the final projection
// is a plain flat GEMM. 64 rows x 64 cols per block, BK=16.
// ---------------------------------------------------------------------------
__global__ __launch_bounds__(256) void gemm_ctx(const float* __restrict__ P,
                                                const float* __restrict__ Vh,
                                                float* __restrict__ C) {
  __shared__ float As[16][65];  // [k][m] transposed store
  __shared__ float Bs[16][68];  // [k][n] direct store; 68 keeps float4 rows 16B-aligned
  const int bh = blockIdx.y;
  const int b = bh / H_, h = bh % H_;
  const float* Pb = P + (size_t)bh * S_ * S_;
  const float* Vb = Vh + (size_t)bh * S_ * DP_;
  const int bm = blockIdx.x;
  const int tid = threadIdx.x;
  const int tx = tid & 15, ty = tid >> 4;
  const int alm = tid >> 2, alk = (tid & 3) << 2;  // A: 64 rows x 16 k
  const int bk = tid >> 4, bn4 = (tid & 15) << 2;  // B: 16 k-rows x 64 n
  float acc[4][4] = {};
  for (int k0 = 0; k0 < S_; k0 += 16) {
    float4 av = *(const float4*)(Pb + (size_t)(bm * 64 + alm) * S_ + k0 + alk);
    float4 bv = *(const float4*)(Vb + (size_t)(k0 + bk) * DP_ + bn4);
    __syncthreads();
    As[alk + 0][alm] = av.x; As[alk + 1][alm] = av.y;
    As[alk + 2][alm] = av.z; As[alk + 3][alm] = av.w;
    *(float4*)&Bs[bk][bn4] = bv;
    __syncthreads();
#pragma unroll
    for (int kk = 0; kk < 16; ++kk) {
      float a[4], bb[4];
#pragma unroll
      for (int i = 0; i < 4; ++i) a[i] = As[kk][ty * 4 + i];
#pragma unroll
      for (int j = 0; j < 4; ++j) bb[j] = Bs[kk][tx * 4 + j];
#pragma unroll
      for (int i = 0; i < 4; ++i)
#pragma unroll
        for (int j = 0; j < 4; ++j) acc[i][j] += a[i] * bb[j];
    }
  }
#pragma unroll
  for (int i = 0; i < 4; ++i) {
    const int q = bm * 64 + ty * 4 + i;
    float4 o;
    o.x = acc[i][0]; o.y = acc[i][1]; o.z = acc[i][2]; o.w = acc[i][3];
    // concat layout: C[b][q][h*64 + d]
    *(float4*)(C + ((size_t)(b * S_ + q) * H_ + h) * DP_ + tx * 4) = o;
  }
}

extern "C" void kernel_launch(void* const* d_in, const int* in_sizes, int n_in,
                              void* d_out, int out_size, void* d_ws, size_t ws_size,
                              hipStream_t stream) {
  (void)in_sizes; (void)n_in; (void)out_size; (void)ws_size;
  const float* q = (const float*)d_in[0];
  const float* k = (const float*)d_in[1];
  const float* v = (const float*)d_in[2];
  const int* mask = (const int*)d_in[3];
  const float* wq_w = (const float*)d_in[4];
  const float* wq_b = (const float*)d_in[5];
  const float* wk_w = (const float*)d_in[6];
  const float* wk_b = (const float*)d_in[7];
  const float* wv_w = (const float*)d_in[8];
  const float* wv_b = (const float*)d_in[9];
  const float* wo_w = (const float*)d_in[10];
  const float* wo_b = (const float*)d_in[11];

  float* out = (float*)d_out;
  float* attn = (float*)d_out + OUT_ELEMS;

  float* qh = (float*)d_ws;           // [B,H,S,64]
  float* kh = qh + HS_ELEMS;
  float* vh = kh + HS_ELEMS;
  float* ctx = vh + HS_ELEMS;         // [B,S,768] concat layout

  const dim3 gproj(M_ / 64, D_ / 64);
  gemm_xwt<true><<<gproj, 256, 0, stream>>>(q, wq_w, wq_b, qh);
  gemm_xwt<true><<<gproj, 256, 0, stream>>>(k, wk_w, wk_b, kh);
  gemm_xwt<true><<<gproj, 256, 0, stream>>>(v, wv_w, wv_b, vh);

  const dim3 gsc(S_ / 64, S_ / 64, B_ * H_);
  gemm_scores<<<gsc, 256, 0, stream>>>(qh, kh, attn);

  softmax_rows<<<dim3(B_ * H_ * S_), 256, 0, stream>>>(attn, mask);

  const dim3 gctx(S_ / 64, B_ * H_);
  gemm_ctx<<<gctx, 256, 0, stream>>>(attn, vh, ctx);

  gemm_xwt<false><<<gproj, 256, 0, stream>>>(ctx, wo_w, wo_b, out);
}